// Round 4
// baseline (72.084 us; speedup 1.0000x reference)
//
#include <hip/hip_runtime.h>

// SpectralPooling via split-bf16 MFMA.
// y = A x_D A x_H A x_W x, A = 48x64 composed (truncate32 + iDCT48) matrix.
// All stages use v_mfma_f32_16x16x32_bf16 tiles (M,N=16, K=32).
// Fragment layouts (m89-verified): A-op: row=lane&15, k=8*(lane>>4)+j.
// B-op: col=lane&15, k=8*(lane>>4)+j. D: col=lane&15, row=4*(lane>>4)+reg.

typedef __attribute__((ext_vector_type(8))) short short8;
typedef __attribute__((ext_vector_type(4))) float f32x4;
typedef __attribute__((ext_vector_type(4))) unsigned int u32x4;

static __device__ __forceinline__ unsigned short f2bf(float f) {
    unsigned int u = __float_as_uint(f);
    u += 0x7fffu + ((u >> 16) & 1u);          // RNE
    return (unsigned short)(u >> 16);
}
static __device__ __forceinline__ float bf2f(unsigned short h) {
    return __uint_as_float(((unsigned int)h) << 16);
}

// Table: tbl[s][ks][t][lane][j], s=hi/lo split, ks=k-step(32), t=16-col tile.
// Element = split_s( At[k][a] ), k = 8*(lane>>4)+j+32*ks, a = 16*t+(lane&15).
// Same lane layout serves both A-op and B-op roles (identical index formula).
static __device__ __forceinline__ short8 ldtbl(const unsigned short* __restrict__ tbl,
                                               int s, int ks, int t, int l) {
    return *(const short8*)(tbl + (((s * 2 + ks) * 3 + t) * 64 + l) * 8);
}

__global__ __launch_bounds__(256) void gen_tbl(unsigned short* __restrict__ tbl) {
    int i = blockIdx.x * 256 + threadIdx.x;     // 0..3071, bijective with (ks,t,lane,j)
    int j = i & 7;
    int lane = (i >> 3) & 63;
    int tks = i >> 9;                           // ks*3 + t
    int t = tks % 3, ks = tks / 3;
    int k = 8 * (lane >> 4) + j + 32 * ks;      // 0..63
    int a = 16 * t + (lane & 15);               // 0..47
    const float PI = 3.14159265358979323846f;
    const float s48 = 0.20412414523193150818f;  // sqrt(2/48)
    const float s64 = 0.17677669529663688110f;  // sqrt(2/64)
    float s = 0.f;
    for (int kk = 0; kk < 32; ++kk) {
        int m48 = ((2 * a + 1) * kk) % 192;     // exact angle reduction mod 4N
        int m64 = ((2 * k + 1) * kk) % 256;
        float c48 = cosf(PI * (float)m48 / 96.0f) * s48;
        float c64 = cosf(PI * (float)m64 / 128.0f) * s64;
        if (kk == 0) { c48 *= 0.70710678118654752440f; c64 *= 0.70710678118654752440f; }
        s += c48 * c64;
    }
    unsigned short hi = f2bf(s);
    unsigned short lo = f2bf(s - bf2f(hi));
    tbl[i] = hi;            // s=0 slab
    tbl[i + 3072] = lo;     // s=1 slab
}

// ---------------- K1: per (bc,d) slice: W then H, both on MFMA ----------------
__global__ __launch_bounds__(256) void k1_wh(const float* __restrict__ x,
                                             const unsigned short* __restrict__ tbl,
                                             unsigned short* __restrict__ y2) {
    __shared__ unsigned int sC[48 * 68];   // C1^T [a2][h], packed hi|lo<<16, stride 68 u32

    const int tid = threadIdx.x;
    const int blk = blockIdx.x;                         // bc*64 + d
    const int g = __builtin_amdgcn_readfirstlane(tid >> 6);
    const int l = tid & 63;
    const int r = l & 15;
    const int kq = l >> 4;

    // ---- stage W: C1[h][a2] = sum_w x[h][w] * At[w][a2]; wave g owns h rows [16g,16g+16)
    f32x4 z = {0.f, 0.f, 0.f, 0.f};
    f32x4 acc0 = z, acc1 = z, acc2 = z;
    const float* xb = x + (size_t)blk * 4096 + (size_t)(16 * g + r) * 64 + kq * 8;
    #pragma unroll
    for (int ks = 0; ks < 2; ++ks) {
        float4 xa = *(const float4*)(xb + 32 * ks);
        float4 xc = *(const float4*)(xb + 32 * ks + 4);
        float v[8] = {xa.x, xa.y, xa.z, xa.w, xc.x, xc.y, xc.z, xc.w};
        short8 xh, xl;
        #pragma unroll
        for (int j = 0; j < 8; ++j) {
            unsigned short h = f2bf(v[j]);
            xh[j] = (short)h;
            xl[j] = (short)f2bf(v[j] - bf2f(h));
        }
        #pragma unroll
        for (int t = 0; t < 3; ++t) {
            short8 wh = ldtbl(tbl, 0, ks, t, l);
            short8 wl = ldtbl(tbl, 1, ks, t, l);
            f32x4 a = (t == 0) ? acc0 : (t == 1) ? acc1 : acc2;
            a = __builtin_amdgcn_mfma_f32_16x16x32_bf16(xh, wh, a, 0, 0, 0);
            a = __builtin_amdgcn_mfma_f32_16x16x32_bf16(xl, wh, a, 0, 0, 0);
            a = __builtin_amdgcn_mfma_f32_16x16x32_bf16(xh, wl, a, 0, 0, 0);
            if (t == 0) acc0 = a; else if (t == 1) acc1 = a; else acc2 = a;
        }
    }
    // store C1^T packed (hi,lo) to LDS: lane holds C1[h=16g+4kq+rr][a2=16t+r]
    #pragma unroll
    for (int t = 0; t < 3; ++t) {
        f32x4 a = (t == 0) ? acc0 : (t == 1) ? acc1 : acc2;
        u32x4 pk;
        #pragma unroll
        for (int rr = 0; rr < 4; ++rr) {
            float vv = a[rr];
            unsigned short h = f2bf(vv);
            unsigned short lo = f2bf(vv - bf2f(h));
            pk[rr] = (unsigned int)h | ((unsigned int)lo << 16);
        }
        *(u32x4*)&sC[(16 * t + r) * 68 + 16 * g + 4 * kq] = pk;   // 4 consecutive h
    }
    __syncthreads();

    // ---- stage H: C2[a1][a2] = sum_h At[h][a1] * C1[h][a2]
    auto loadB = [&](int n, int ks, short8& ch, short8& cl) {
        const unsigned int* bp = &sC[(16 * n + r) * 68 + 8 * kq + 32 * ks];
        u32x4 u0 = *(const u32x4*)bp;
        u32x4 u1 = *(const u32x4*)(bp + 4);
        #pragma unroll
        for (int e = 0; e < 4; ++e) {
            ch[e]     = (short)(u0[e] & 0xffffu);
            cl[e]     = (short)(u0[e] >> 16);
            ch[4 + e] = (short)(u1[e] & 0xffffu);
            cl[4 + e] = (short)(u1[e] >> 16);
        }
    };
    auto storeY = [&](int m, int n, f32x4 c) {
        unsigned short* dst = y2 + (size_t)blk * 2304 + (size_t)(16 * m + 4 * kq) * 48 + 16 * n + r;
        #pragma unroll
        for (int rr = 0; rr < 4; ++rr) dst[(size_t)rr * 48] = f2bf(c[rr]);
    };

    if (g < 3) {
        // wave g: tiles (m=g, n=0) and (m=g, n=1)
        f32x4 c0 = z, c1 = z;
        #pragma unroll
        for (int ks = 0; ks < 2; ++ks) {
            short8 ah = ldtbl(tbl, 0, ks, g, l);
            short8 al = ldtbl(tbl, 1, ks, g, l);
            short8 ch, cl;
            loadB(0, ks, ch, cl);
            c0 = __builtin_amdgcn_mfma_f32_16x16x32_bf16(ah, ch, c0, 0, 0, 0);
            c0 = __builtin_amdgcn_mfma_f32_16x16x32_bf16(al, ch, c0, 0, 0, 0);
            c0 = __builtin_amdgcn_mfma_f32_16x16x32_bf16(ah, cl, c0, 0, 0, 0);
            loadB(1, ks, ch, cl);
            c1 = __builtin_amdgcn_mfma_f32_16x16x32_bf16(ah, ch, c1, 0, 0, 0);
            c1 = __builtin_amdgcn_mfma_f32_16x16x32_bf16(al, ch, c1, 0, 0, 0);
            c1 = __builtin_amdgcn_mfma_f32_16x16x32_bf16(ah, cl, c1, 0, 0, 0);
        }
        storeY(g, 0, c0);
        storeY(g, 1, c1);
    } else {
        // wave 3: column n=2, tiles m=0,1,2 (B-frag shared across m)
        f32x4 t0 = z, t1 = z, t2 = z;
        #pragma unroll
        for (int ks = 0; ks < 2; ++ks) {
            short8 ch, cl;
            loadB(2, ks, ch, cl);
            #pragma unroll
            for (int m = 0; m < 3; ++m) {
                short8 ah = ldtbl(tbl, 0, ks, m, l);
                short8 al = ldtbl(tbl, 1, ks, m, l);
                f32x4 a = (m == 0) ? t0 : (m == 1) ? t1 : t2;
                a = __builtin_amdgcn_mfma_f32_16x16x32_bf16(ah, ch, a, 0, 0, 0);
                a = __builtin_amdgcn_mfma_f32_16x16x32_bf16(al, ch, a, 0, 0, 0);
                a = __builtin_amdgcn_mfma_f32_16x16x32_bf16(ah, cl, a, 0, 0, 0);
                if (m == 0) t0 = a; else if (m == 1) t1 = a; else t2 = a;
            }
        }
        storeY(0, 2, t0);
        storeY(1, 2, t1);
        storeY(2, 2, t2);
    }
}

// ---------------- K2: D-transform, LDS-staged, swapped operands ----------------
// out[bc][a0][a1][a2] = sum_d y2[bc][d][a1][a2] * At[d][a0]
// A-op = y2 fragment (row=a2-in-tile, k=d), B-op = tbl (col=a0-in-tile, k=d).
// D: col=lane&15 -> a0, row=4*kq+rr -> a2  => 4 consecutive a2 per lane = float4 store.
__global__ __launch_bounds__(256) void k2_d(const unsigned short* __restrict__ y2,
                                            const unsigned short* __restrict__ tbl,
                                            float* __restrict__ out) {
    __shared__ unsigned short sY[4 * 3 * 64 * 16];   // [a1l][m][d][c] = 24 KB

    const int tid = threadIdx.x;
    const int blk = blockIdx.x;            // bc*12 + quad
    const int bc = blk / 12;
    const int quad = blk % 12;

    // ---- stage: y2 tile (all d, 4 a1, all a2) -> LDS, coalesced float4 loads
    const unsigned short* yb = y2 + (size_t)bc * 64 * 2304 + (size_t)quad * 4 * 48;
    #pragma unroll
    for (int jj = 0; jj < 6; ++jj) {
        int f = tid + 256 * jj;            // 0..1535 (16B chunks)
        int d = f / 24;                    // 24 float4 per d
        int p = f % 24;
        int a1l = p / 6;                   // 6 float4 per a1-row (48 u16)
        int q = p % 6;
        int a2 = q * 8;
        int m = a2 >> 4;
        int c0 = a2 & 15;
        u32x4 v = *(const u32x4*)(yb + (size_t)d * 2304 + a1l * 48 + a2);
        *(u32x4*)&sY[(((a1l * 3 + m) * 64) + d) * 16 + c0] = v;
    }
    __syncthreads();

    const int g = __builtin_amdgcn_readfirstlane(tid >> 6);   // wave -> a1 local
    const int l = tid & 63;
    const int r = l & 15;
    const int kq = l >> 4;
    const int a1 = quad * 4 + g;

    // hoist B-frags (constant table, L1-hot)
    short8 th[2][3], tl[2][3];
    #pragma unroll
    for (int ks = 0; ks < 2; ++ks)
        #pragma unroll
        for (int n = 0; n < 3; ++n) {
            th[ks][n] = ldtbl(tbl, 0, ks, n, l);
            tl[ks][n] = ldtbl(tbl, 1, ks, n, l);
        }

    f32x4 z = {0.f, 0.f, 0.f, 0.f};
    f32x4 acc[3][3];
    #pragma unroll
    for (int m = 0; m < 3; ++m)
        #pragma unroll
        for (int n = 0; n < 3; ++n) acc[m][n] = z;

    #pragma unroll
    for (int m = 0; m < 3; ++m) {
        #pragma unroll
        for (int ks = 0; ks < 2; ++ks) {
            short8 ya;     // A-frag: row=a2=16m+r, k=d=8kq+j+32ks
            #pragma unroll
            for (int j = 0; j < 8; ++j)
                ya[j] = (short)sY[((g * 3 + m) * 64 + 8 * kq + 32 * ks + j) * 16 + r];
            #pragma unroll
            for (int n = 0; n < 3; ++n) {
                acc[m][n] = __builtin_amdgcn_mfma_f32_16x16x32_bf16(ya, th[ks][n], acc[m][n], 0, 0, 0);
                acc[m][n] = __builtin_amdgcn_mfma_f32_16x16x32_bf16(ya, tl[ks][n], acc[m][n], 0, 0, 0);
            }
        }
    }

    // ---- store: lane (kq,r), tile (m,n): out[a0=16n+r][a1][a2=16m+4kq+rr], rr=0..3
    #pragma unroll
    for (int m = 0; m < 3; ++m)
        #pragma unroll
        for (int n = 0; n < 3; ++n) {
            float4 v;
            v.x = acc[m][n][0]; v.y = acc[m][n][1]; v.z = acc[m][n][2]; v.w = acc[m][n][3];
            float* dst = out + ((size_t)(bc * 48 + 16 * n + r) * 48 + a1) * 48 + 16 * m + 4 * kq;
            *(float4*)dst = v;
        }
}

extern "C" void kernel_launch(void* const* d_in, const int* in_sizes, int n_in,
                              void* d_out, int out_size, void* d_ws, size_t ws_size,
                              hipStream_t stream) {
    const float* x = (const float*)d_in[0];
    float* out = (float*)d_out;

    unsigned short* tbl = (unsigned short*)d_ws;                     // 12 KiB
    unsigned short* y2 = (unsigned short*)((char*)d_ws + 65536);     // 36.75 MiB bf16

    gen_tbl<<<12, 256, 0, stream>>>(tbl);
    k1_wh<<<128 * 64, 256, 0, stream>>>(x, tbl, y2);
    k2_d<<<128 * 12, 256, 0, stream>>>(y2, tbl, out);
}

// Round 5
// 61.257 us; speedup vs baseline: 1.1767x; 1.1767x over previous
//
#include <hip/hip_runtime.h>

// SpectralPooling via split-bf16 MFMA.
// y = A x_D A x_H A x_W x, A = 48x64 composed (truncate32 + iDCT48) matrix.
// All stages use v_mfma_f32_16x16x32_bf16 (M,N=16, K=32).
// Layouts (m89-verified): A-op row=lane&15, k=8*(lane>>4)+j.
// B-op col=lane&15, k=8*(lane>>4)+j. D: col=lane&15, row=4*(lane>>4)+reg.
// k1 keeps DATA split (x, C1 as hi+lo bf16) but single-bf16 MATRIX (drop
// matrix-lo terms: ~1e-3 RMS error, budget 6.4e-2).

typedef __attribute__((ext_vector_type(8))) short short8;
typedef __attribute__((ext_vector_type(4))) float f32x4;
typedef __attribute__((ext_vector_type(4))) unsigned int u32x4;
typedef __attribute__((ext_vector_type(2))) unsigned int u32x2;

static __device__ __forceinline__ unsigned short f2bf(float f) {
    unsigned int u = __float_as_uint(f);
    u += 0x7fffu + ((u >> 16) & 1u);          // RNE
    return (unsigned short)(u >> 16);
}
static __device__ __forceinline__ float bf2f(unsigned short h) {
    return __uint_as_float(((unsigned int)h) << 16);
}

// Table: tbl[s][ks][t][lane][j], s=hi/lo split, ks=k-step(32), t=16-col tile.
// Element = split_s( At[k][a] ), k = 8*(lane>>4)+j+32*ks, a = 16*t+(lane&15).
// Same lane layout serves both A-op and B-op roles.
static __device__ __forceinline__ short8 ldtbl(const unsigned short* __restrict__ tbl,
                                               int s, int ks, int t, int l) {
    return *(const short8*)(tbl + (unsigned)((((s * 2 + ks) * 3 + t) * 64 + l) * 8));
}

__global__ __launch_bounds__(256) void gen_tbl(unsigned short* __restrict__ tbl) {
    int i = blockIdx.x * 256 + threadIdx.x;     // 0..3071
    int j = i & 7;
    int lane = (i >> 3) & 63;
    int tks = i >> 9;                           // ks*3 + t
    int t = tks % 3, ks = tks / 3;
    int k = 8 * (lane >> 4) + j + 32 * ks;      // 0..63
    int a = 16 * t + (lane & 15);               // 0..47
    const float PI = 3.14159265358979323846f;
    const float s48 = 0.20412414523193150818f;  // sqrt(2/48)
    const float s64 = 0.17677669529663688110f;  // sqrt(2/64)
    float s = 0.f;
    for (int kk = 0; kk < 32; ++kk) {
        int m48 = ((2 * a + 1) * kk) % 192;     // exact angle reduction mod 4N
        int m64 = ((2 * k + 1) * kk) % 256;
        float c48 = cosf(PI * (float)m48 / 96.0f) * s48;
        float c64 = cosf(PI * (float)m64 / 128.0f) * s64;
        if (kk == 0) { c48 *= 0.70710678118654752440f; c64 *= 0.70710678118654752440f; }
        s += c48 * c64;
    }
    unsigned short hi = f2bf(s);
    unsigned short lo = f2bf(s - bf2f(hi));
    tbl[i] = hi;            // s=0 slab
    tbl[i + 3072] = lo;     // s=1 slab
}

// ---------------- K1: per (bc,d) slice: W then H, both on MFMA ----------------
__global__ __launch_bounds__(256) void k1_wh(const float* __restrict__ x,
                                             const unsigned short* __restrict__ tbl,
                                             unsigned short* __restrict__ y2) {
    __shared__ unsigned int sC[48 * 68];   // C1^T [a2][h], packed hi|lo<<16, stride 68 u32

    const int tid = threadIdx.x;
    const int blk = blockIdx.x;                         // bc*64 + d
    const int g = __builtin_amdgcn_readfirstlane(tid >> 6);
    const int l = tid & 63;
    const int r = l & 15;
    const int kq = l >> 4;

    // ---- stage W: C1[h][a2] = sum_w x[h][w] * At[w][a2]; wave g owns h rows [16g,16g+16)
    f32x4 z = {0.f, 0.f, 0.f, 0.f};
    f32x4 acc0 = z, acc1 = z, acc2 = z;
    const float* xb = x + (unsigned)(blk * 4096 + (16 * g + r) * 64 + kq * 8);
    #pragma unroll
    for (int ks = 0; ks < 2; ++ks) {
        float4 xa = *(const float4*)(xb + 32 * ks);
        float4 xc = *(const float4*)(xb + 32 * ks + 4);
        float v[8] = {xa.x, xa.y, xa.z, xa.w, xc.x, xc.y, xc.z, xc.w};
        short8 xh, xl;
        #pragma unroll
        for (int j = 0; j < 8; ++j) {
            // truncation split: hi = chop(f), lo = chop(f - hi)
            unsigned int u = __float_as_uint(v[j]);
            float rem = v[j] - __uint_as_float(u & 0xffff0000u);
            xh[j] = (short)(u >> 16);
            xl[j] = (short)(__float_as_uint(rem) >> 16);
        }
        #pragma unroll
        for (int t = 0; t < 3; ++t) {
            short8 wh = ldtbl(tbl, 0, ks, t, l);
            f32x4 a = (t == 0) ? acc0 : (t == 1) ? acc1 : acc2;
            a = __builtin_amdgcn_mfma_f32_16x16x32_bf16(xh, wh, a, 0, 0, 0);
            a = __builtin_amdgcn_mfma_f32_16x16x32_bf16(xl, wh, a, 0, 0, 0);
            if (t == 0) acc0 = a; else if (t == 1) acc1 = a; else acc2 = a;
        }
    }
    // store C1^T packed (hi|lo) to LDS: lane holds C1[h=16g+4kq+rr][a2=16t+r]
    #pragma unroll
    for (int t = 0; t < 3; ++t) {
        f32x4 a = (t == 0) ? acc0 : (t == 1) ? acc1 : acc2;
        u32x4 pk;
        #pragma unroll
        for (int rr = 0; rr < 4; ++rr) {
            unsigned int u = __float_as_uint(a[rr]);
            float rem = a[rr] - __uint_as_float(u & 0xffff0000u);
            pk[rr] = (u >> 16) | (__float_as_uint(rem) & 0xffff0000u);
        }
        *(u32x4*)&sC[(16 * t + r) * 68 + 16 * g + 4 * kq] = pk;   // 4 consecutive h
    }
    __syncthreads();

    // ---- stage H (swapped operands): C2[a2][a1] = sum_h C1[h][a2] * At[h][a1]
    // A-op = C1 frag (row=a2, k=h), B-op = tbl (col=a1, k=h).
    // D: row(4kq+rr)=a2-local -> 4 consecutive a2 per lane => 8B stores.
    auto loadA = [&](int m, int ks, short8& ch, short8& cl) {
        const unsigned int* bp = &sC[(16 * m + r) * 68 + 8 * kq + 32 * ks];
        u32x4 u0 = *(const u32x4*)bp;
        u32x4 u1 = *(const u32x4*)(bp + 4);
        #pragma unroll
        for (int e = 0; e < 4; ++e) {
            ch[e]     = (short)(u0[e] & 0xffffu);
            cl[e]     = (short)(u0[e] >> 16);
            ch[4 + e] = (short)(u1[e] & 0xffffu);
            cl[4 + e] = (short)(u1[e] >> 16);
        }
    };
    auto storeY = [&](int m, int n, f32x4 c) {
        // a2 = 16m + 4kq + rr (consecutive), a1 = 16n + r
        u32x2 pk;
        pk[0] = (unsigned int)f2bf(c[0]) | ((unsigned int)f2bf(c[1]) << 16);
        pk[1] = (unsigned int)f2bf(c[2]) | ((unsigned int)f2bf(c[3]) << 16);
        *(u32x2*)(y2 + (unsigned)(blk * 2304 + (16 * n + r) * 48 + 16 * m + 4 * kq)) = pk;
    };

    if (g < 3) {
        // wave g: column n=g (a1-tile), rows m=0,1 (a2-tiles)
        f32x4 c0 = z, c1 = z;
        #pragma unroll
        for (int ks = 0; ks < 2; ++ks) {
            short8 ah = ldtbl(tbl, 0, ks, g, l);
            short8 ch, cl;
            loadA(0, ks, ch, cl);
            c0 = __builtin_amdgcn_mfma_f32_16x16x32_bf16(ch, ah, c0, 0, 0, 0);
            c0 = __builtin_amdgcn_mfma_f32_16x16x32_bf16(cl, ah, c0, 0, 0, 0);
            loadA(1, ks, ch, cl);
            c1 = __builtin_amdgcn_mfma_f32_16x16x32_bf16(ch, ah, c1, 0, 0, 0);
            c1 = __builtin_amdgcn_mfma_f32_16x16x32_bf16(cl, ah, c1, 0, 0, 0);
        }
        storeY(0, g, c0);
        storeY(1, g, c1);
    } else {
        // wave 3: row m=2 (a2-tile), all columns n=0..2 (A-frag shared across n)
        f32x4 t0 = z, t1 = z, t2 = z;
        #pragma unroll
        for (int ks = 0; ks < 2; ++ks) {
            short8 ch, cl;
            loadA(2, ks, ch, cl);
            #pragma unroll
            for (int n = 0; n < 3; ++n) {
                short8 ah = ldtbl(tbl, 0, ks, n, l);
                f32x4 a = (n == 0) ? t0 : (n == 1) ? t1 : t2;
                a = __builtin_amdgcn_mfma_f32_16x16x32_bf16(ch, ah, a, 0, 0, 0);
                a = __builtin_amdgcn_mfma_f32_16x16x32_bf16(cl, ah, a, 0, 0, 0);
                if (n == 0) t0 = a; else if (n == 1) t1 = a; else t2 = a;
            }
        }
        storeY(2, 0, t0);
        storeY(2, 1, t1);
        storeY(2, 2, t2);
    }
}

// ---------------- K2: D-transform, LDS-staged, swapped operands ----------------
// out[bc][a0][a1][a2] = sum_d y2[bc][d][a1][a2] * At[d][a0]
// A-op = y2 fragment (row=a2-in-tile, k=d), B-op = tbl (col=a0-in-tile, k=d).
__global__ __launch_bounds__(256) void k2_d(const unsigned short* __restrict__ y2,
                                            const unsigned short* __restrict__ tbl,
                                            float* __restrict__ out) {
    __shared__ unsigned short sY[4 * 3 * 64 * 16];   // [a1l][m][d][c] = 24 KB

    const int tid = threadIdx.x;
    const int blk = blockIdx.x;            // bc*12 + quad
    const int bc = blk / 12;
    const int quad = blk % 12;

    // ---- stage: y2 tile (all d, 4 a1, all a2) -> LDS, coalesced 16B loads
    const unsigned short* yb = y2 + (unsigned)(bc * 64 * 2304 + quad * 4 * 48);
    #pragma unroll
    for (int jj = 0; jj < 6; ++jj) {
        int f = tid + 256 * jj;            // 0..1535 (16B chunks)
        int d = f / 24;                    // 24 chunks per d
        int p = f % 24;
        int a1l = p / 6;                   // 6 chunks per a1-row (48 u16)
        int q = p % 6;
        int a2 = q * 8;
        int m = a2 >> 4;
        int c0 = a2 & 15;
        u32x4 v = *(const u32x4*)(yb + (unsigned)(d * 2304 + a1l * 48 + a2));
        *(u32x4*)&sY[(((a1l * 3 + m) * 64) + d) * 16 + c0] = v;
    }
    __syncthreads();

    const int g = __builtin_amdgcn_readfirstlane(tid >> 6);   // wave -> a1 local
    const int l = tid & 63;
    const int r = l & 15;
    const int kq = l >> 4;
    const int a1 = quad * 4 + g;

    // hoist B-frags (constant table, L1-hot)
    short8 th[2][3], tl[2][3];
    #pragma unroll
    for (int ks = 0; ks < 2; ++ks)
        #pragma unroll
        for (int n = 0; n < 3; ++n) {
            th[ks][n] = ldtbl(tbl, 0, ks, n, l);
            tl[ks][n] = ldtbl(tbl, 1, ks, n, l);
        }

    f32x4 z = {0.f, 0.f, 0.f, 0.f};
    f32x4 acc[3][3];
    #pragma unroll
    for (int m = 0; m < 3; ++m)
        #pragma unroll
        for (int n = 0; n < 3; ++n) acc[m][n] = z;

    #pragma unroll
    for (int m = 0; m < 3; ++m) {
        #pragma unroll
        for (int ks = 0; ks < 2; ++ks) {
            short8 ya;     // A-frag: row=a2=16m+r, k=d=8kq+j+32ks
            #pragma unroll
            for (int j = 0; j < 8; ++j)
                ya[j] = (short)sY[((g * 3 + m) * 64 + 8 * kq + 32 * ks + j) * 16 + r];
            #pragma unroll
            for (int n = 0; n < 3; ++n) {
                acc[m][n] = __builtin_amdgcn_mfma_f32_16x16x32_bf16(ya, th[ks][n], acc[m][n], 0, 0, 0);
                acc[m][n] = __builtin_amdgcn_mfma_f32_16x16x32_bf16(ya, tl[ks][n], acc[m][n], 0, 0, 0);
            }
        }
    }

    // ---- store: lane (kq,r), tile (m,n): out[a0=16n+r][a1][a2=16m+4kq+rr]
    #pragma unroll
    for (int m = 0; m < 3; ++m)
        #pragma unroll
        for (int n = 0; n < 3; ++n) {
            float4 v;
            v.x = acc[m][n][0]; v.y = acc[m][n][1]; v.z = acc[m][n][2]; v.w = acc[m][n][3];
            float* dst = out + ((size_t)(bc * 48 + 16 * n + r) * 48 + a1) * 48 + 16 * m + 4 * kq;
            *(float4*)dst = v;
        }
}

extern "C" void kernel_launch(void* const* d_in, const int* in_sizes, int n_in,
                              void* d_out, int out_size, void* d_ws, size_t ws_size,
                              hipStream_t stream) {
    const float* x = (const float*)d_in[0];
    float* out = (float*)d_out;

    unsigned short* tbl = (unsigned short*)d_ws;                     // 12 KiB
    unsigned short* y2 = (unsigned short*)((char*)d_ws + 65536);     // 36.75 MiB bf16

    gen_tbl<<<12, 256, 0, stream>>>(tbl);
    k1_wh<<<128 * 64, 256, 0, stream>>>(x, tbl, y2);
    k2_d<<<128 * 12, 256, 0, stream>>>(y2, tbl, out);
}